// Round 2
// baseline (625.444 us; speedup 1.0000x reference)
//
#include <hip/hip_runtime.h>

constexpr int B  = 32;
constexpr int C  = 3072;
constexpr int HW = 784;
constexpr int K  = 11;
constexpr int NC = 200;

// d_out layout (floats), concatenated in reference return order
constexpr int AFM_OFF    = 0;         // B*C*K  = 1081344
constexpr int SCORES_OFF = 1081344;   // B*NC   = 6400
constexpr int MAPS_OFF   = 1087744;   // B*K*HW = 275968
constexpr int ATTN_OFF   = 1363712;   // B*K    = 352

// ws layout (floats)
constexpr int WT_OFF   = 0;       // C*12 : w_land transposed, scaled by 2, padded to 12/row
constexpr int ASQ_OFF  = 36864;   // 16   : a_sq[k]
constexpr int FSUM_OFF = 36880;   // B*C  : sum over k of afm (modulated, /HW)

// ---------------------------------------------------------------- K0: prep
// blocks 0..10: a_sq[k] = sum_c w[k][c]^2 ; blocks 11..22: wT[c][k] = 2*w[k][c]
__global__ __launch_bounds__(256) void k0_prep(const float* __restrict__ w_land,
                                               float* __restrict__ ws) {
  const int bid = blockIdx.x;
  const int t = threadIdx.x;
  if (bid < K) {
    const int k = bid;
    float s = 0.f;
    for (int c = t; c < C; c += 256) {
      float v = w_land[k * C + c];
      s = fmaf(v, v, s);
    }
    __shared__ float red[256];
    red[t] = s;
    __syncthreads();
    for (int off = 128; off > 0; off >>= 1) {
      if (t < off) red[t] += red[t + off];
      __syncthreads();
    }
    if (t == 0) ws[ASQ_OFF + k] = red[0];
  } else {
    const int c = (bid - K) * 256 + t;
    #pragma unroll
    for (int k = 0; k < K; k++)
      ws[WT_OFF + c * 12 + k] = 2.f * w_land[k * C + c];
    ws[WT_OFF + c * 12 + K] = 0.f;
  }
}

// ---------------------------------------------------------------- K1: maps + attn
// grid = B*16 blocks of 512 threads (exactly 2 blocks/CU on 256 CUs).
// hw tiles are 64B-cache-line aligned: tile0 = [0,64), tile i>=1 = [16+48i, 64+48i).
// Wave g owns the contiguous channel slab [g*384, (g+1)*384) -> sequential wT
// scalar streaming + DRAM-local x reads. logits = sum_c 2w[k][c]*x[c] - a_sq[k]
// (b_sq cancels in the K-softmax). Per-thread softmax over K=11 registers.
__global__ __launch_bounds__(512) void k1_maps(const float* __restrict__ x,
                                               const float* __restrict__ ws,
                                               float* __restrict__ maps_out,
                                               float* __restrict__ attn_out) {
  const int bid  = blockIdx.x;
  const int b    = bid >> 4;
  const int tile = bid & 15;
  const int t    = threadIdx.x;
  const int g    = __builtin_amdgcn_readfirstlane(t >> 6);  // wave id, uniform
  const int hwl  = t & 63;
  const int hw0  = (tile == 0) ? 0 : 16 + tile * 48;
  const int tsz  = (tile == 0) ? 64 : 48;
  const bool valid = hwl < tsz;
  const int hw   = hw0 + (valid ? hwl : (tsz - 1));  // clamp; results discarded

  const float* xp  = x + (size_t)b * C * HW + hw;
  const float* wT  = ws + WT_OFF;
  const float* asq = ws + ASQ_OFF;

  float acc[K];
  #pragma unroll
  for (int k = 0; k < K; k++) acc[k] = (g == 0) ? -asq[k] : 0.f;

  const int cbase = g * (C / 8);   // contiguous 384-channel slab per wave
  // 384 channels per thread, unroll 8 -> 8 coalesced loads in flight
  for (int i0 = 0; i0 < C / 8; i0 += 8) {
    float xv[8];
    #pragma unroll
    for (int u = 0; u < 8; u++)
      xv[u] = xp[(size_t)(cbase + i0 + u) * HW];
    #pragma unroll
    for (int u = 0; u < 8; u++) {
      const float* wrow = wT + (cbase + i0 + u) * 12;  // uniform -> s_load
      #pragma unroll
      for (int k = 0; k < K; k++) acc[k] = fmaf(wrow[k], xv[u], acc[k]);
    }
  }

  __shared__ float abp[8][K][64];
  #pragma unroll
  for (int k = 0; k < K; k++) abp[g][k][hwl] = acc[k];
  __syncthreads();

  if (g == 0) {
    float l[K];
    #pragma unroll
    for (int k = 0; k < K; k++) {
      float s = 0.f;
      #pragma unroll
      for (int gg = 0; gg < 8; gg++) s += abp[gg][k][hwl];
      l[k] = s;
    }
    float m = l[0];
    #pragma unroll
    for (int k = 1; k < K; k++) m = fmaxf(m, l[k]);
    float z = 0.f;
    #pragma unroll
    for (int k = 0; k < K; k++) { l[k] = __expf(l[k] - m); z += l[k]; }
    const float inv = 1.f / z;
    #pragma unroll
    for (int k = 0; k < K; k++) {
      float r = l[k] * inv;
      if (valid) maps_out[((size_t)b * K + k) * HW + hw] = r;
      float v = valid ? r : 0.f;
      #pragma unroll
      for (int sh = 32; sh > 0; sh >>= 1) v += __shfl_xor(v, sh);
      if (hwl == 0) atomicAdd(&attn_out[b * K + k], v);
    }
  }
}

// ---------------------------------------------------------------- K2: all_features (+ fused fsum)
// grid = B*24, 256 threads. Block owns (b, 128-channel tile), streams hw in
// 64-chunks through an LDS transpose (row stride 68 floats = odd multiple of
// 16B -> conflict-free b128 reads). maps[b] lives in LDS, zero-padded past
// hw=784. Staging is float4 via a register-prefetch pipeline: chunk ch+1's
// global loads are issued before computing chunk ch, ds_write after the
// barrier -> HBM latency hides under compute (T14). Thread (p,q) owns
// channels {p, p+64} over hw-quarter q. Blocks walk b in reverse so the x
// re-read hits what K1 left in L3. Epilogue also emits fsum[b,c] (old k3).
constexpr int CT   = 128;
constexpr int XROW = 68;
constexpr int MROW = 832;  // 13*64

__global__ __launch_bounds__(256) void k2_feat(const float* __restrict__ x,
                                               const float* __restrict__ maps_g,
                                               const float* __restrict__ modulation,
                                               float* __restrict__ afm_out,
                                               float* __restrict__ fsum_out) {
  __shared__ __align__(16) float maps_s[K * MROW];   // 36.6 KB
  __shared__ __align__(16) float lds_x[CT * XROW];   // 34.8 KB

  const int bid = blockIdx.x;
  const int b   = (B - 1) - (bid / (C / CT));
  const int c0  = (bid % (C / CT)) * CT;
  const int t   = threadIdx.x;

  // ---- stage maps as float4, zero-padded to MROW
  if (t < MROW / 4) {
    float4 v = make_float4(0.f, 0.f, 0.f, 0.f);
    #pragma unroll
    for (int k = 0; k < K; k++) {
      if (t < HW / 4)
        v = ((const float4*)(maps_g + ((size_t)b * K + k) * HW))[t];
      else
        v = make_float4(0.f, 0.f, 0.f, 0.f);
      ((float4*)(maps_s + k * MROW))[t] = v;
    }
  }

  const int f4l  = t & 15;   // float4 column within 64-hw chunk
  const int rgrp = t >> 4;   // 16 row groups -> rows rgrp + j*16
  const int p    = t & 63;
  const int q    = t >> 6;

  const float4* xb4 = (const float4*)(x + (size_t)b * C * HW);  // rows of HW/4 f4

  float4 pf[8];
  auto stage_load = [&](int ch) {
    const int hb4 = ch * 16;
    int c4 = hb4 + f4l;
    if (c4 >= HW / 4) c4 = HW / 4 - 1;  // clamped garbage * maps_pad(0) = 0
    #pragma unroll
    for (int j = 0; j < 8; j++)
      pf[j] = xb4[(size_t)(c0 + rgrp + j * 16) * (HW / 4) + c4];
  };
  auto stage_write = [&]() {
    #pragma unroll
    for (int j = 0; j < 8; j++)
      *(float4*)&lds_x[(rgrp + j * 16) * XROW + f4l * 4] = pf[j];
  };

  float f0[K], f1[K];
  #pragma unroll
  for (int k = 0; k < K; k++) { f0[k] = 0.f; f1[k] = 0.f; }

  stage_load(0);
  stage_write();
  __syncthreads();   // covers maps_s + chunk0

  for (int ch = 0; ch < 13; ch++) {
    if (ch < 12) stage_load(ch + 1);   // issue next chunk's loads early
    const int hbase = ch * 64;
    #pragma unroll
    for (int hg = 0; hg < 4; hg++) {
      const int hoff = (q * 4 + hg) * 4;
      const float4 xa = *(const float4*)&lds_x[p * XROW + hoff];
      const float4 xc = *(const float4*)&lds_x[(p + 64) * XROW + hoff];
      #pragma unroll
      for (int k = 0; k < K; k++) {
        const float4 m4 = *(const float4*)&maps_s[k * MROW + hbase + hoff];
        f0[k] += xa.x * m4.x + xa.y * m4.y + xa.z * m4.z + xa.w * m4.w;
        f1[k] += xc.x * m4.x + xc.y * m4.y + xc.z * m4.z + xc.w * m4.w;
      }
    }
    __syncthreads();          // everyone done reading lds_x[ch]
    if (ch < 12) {
      stage_write();          // vmcnt wait happens here, latency already hidden
      __syncthreads();        // chunk ch+1 visible
    }
  }

  // reduce the 4 hw-quarters via LDS, then modulate + /HW and store
  float* fbuf = lds_x;  // 4*128*11 = 5632 floats <= 8704 available
  #pragma unroll
  for (int k = 0; k < K; k++) {
    fbuf[(q * CT + p) * K + k]      = f0[k];
    fbuf[(q * CT + p + 64) * K + k] = f1[k];
  }
  __syncthreads();

  const float inv_hw = 1.f / (float)HW;
  for (int o = t; o < CT * K; o += 256) {
    float s = fbuf[o] + fbuf[CT * K + o] + fbuf[2 * CT * K + o] + fbuf[3 * CT * K + o];
    afm_out[(size_t)b * C * K + c0 * K + o] = s * inv_hw * modulation[c0 * K + o];
  }
  // fused k3: fsum[b,c] = sum_k afm_modulated
  for (int cl = t; cl < CT; cl += 256) {
    float s = 0.f;
    #pragma unroll
    for (int k = 0; k < K; k++) {
      const int o = cl * K + k;
      float v = fbuf[o] + fbuf[CT * K + o] + fbuf[2 * CT * K + o] + fbuf[3 * CT * K + o];
      s += v * modulation[c0 * K + o];
    }
    fsum_out[(size_t)b * C + c0 + cl] = s * inv_hw;
  }
}

// ---------------------------------------------------------------- K4: scores
// grid = B*25 blocks; 256 threads = 8 class-rows x 32 lanes. fsum[b] staged in
// LDS (broadcast), w_cls rows read coalesced, 32-lane shuffle reduction.
__global__ __launch_bounds__(256) void k4_scores(const float* __restrict__ fsum,
                                                 const float* __restrict__ w_cls,
                                                 float* __restrict__ scores) {
  __shared__ float fs[C];  // 12 KB
  const int bid = blockIdx.x;
  const int b   = bid / (NC / 8);
  const int nt  = bid % (NC / 8);
  const int t   = threadIdx.x;

  for (int i = t; i < C; i += 256) fs[i] = fsum[b * C + i];
  __syncthreads();

  const int nl = t >> 5, lane = t & 31;
  const int n = nt * 8 + nl;
  const float* wr = w_cls + (size_t)n * C;
  float acc = 0.f;
  for (int c = lane; c < C; c += 32) acc = fmaf(wr[c], fs[c], acc);
  #pragma unroll
  for (int sh = 16; sh > 0; sh >>= 1) acc += __shfl_xor(acc, sh);
  if (lane == 0) scores[b * NC + n] = acc;
}

// ----------------------------------------------------------------
extern "C" void kernel_launch(void* const* d_in, const int* in_sizes, int n_in,
                              void* d_out, int out_size, void* d_ws, size_t ws_size,
                              hipStream_t stream) {
  const float* x          = (const float*)d_in[0];
  const float* w_land     = (const float*)d_in[1];
  const float* modulation = (const float*)d_in[2];
  const float* w_cls      = (const float*)d_in[3];

  float* out    = (float*)d_out;
  float* afm    = out + AFM_OFF;
  float* scores = out + SCORES_OFF;
  float* maps   = out + MAPS_OFF;
  float* attn   = out + ATTN_OFF;
  float* ws     = (float*)d_ws;

  hipMemsetAsync(attn, 0, B * K * sizeof(float), stream);            // attn via atomics
  k0_prep  <<<K + C / 256,     256, 0, stream>>>(w_land, ws);
  k1_maps  <<<B * 16,          512, 0, stream>>>(x, ws, maps, attn);
  k2_feat  <<<B * (C / CT),    256, 0, stream>>>(x, maps, modulation, afm, ws + FSUM_OFF);
  k4_scores<<<B * (NC / 8),    256, 0, stream>>>(ws + FSUM_OFF, w_cls, scores);
}

// Round 3
// 535.577 us; speedup vs baseline: 1.1678x; 1.1678x over previous
//
#include <hip/hip_runtime.h>

constexpr int B  = 32;
constexpr int C  = 3072;
constexpr int HW = 784;
constexpr int K  = 11;
constexpr int NC = 200;

// d_out layout (floats), concatenated in reference return order
constexpr int AFM_OFF    = 0;         // B*C*K  = 1081344
constexpr int SCORES_OFF = 1081344;   // B*NC   = 6400
constexpr int MAPS_OFF   = 1087744;   // B*K*HW = 275968
constexpr int ATTN_OFF   = 1363712;   // B*K    = 352

// ws layout (floats)
constexpr int WT_OFF   = 0;       // C*12 : w_land transposed, scaled by 2, padded to 12/row
constexpr int ASQ_OFF  = 36864;   // 16   : a_sq[k]
constexpr int FSUM_OFF = 36880;   // B*C  : sum over k of afm (modulated, /HW)

// ---------------------------------------------------------------- K0: prep
// blocks 0..10: a_sq[k] = sum_c w[k][c]^2 ; blocks 11..22: wT[c][k] = 2*w[k][c]
__global__ __launch_bounds__(256) void k0_prep(const float* __restrict__ w_land,
                                               float* __restrict__ ws) {
  const int bid = blockIdx.x;
  const int t = threadIdx.x;
  if (bid < K) {
    const int k = bid;
    float s = 0.f;
    for (int c = t; c < C; c += 256) {
      float v = w_land[k * C + c];
      s = fmaf(v, v, s);
    }
    __shared__ float red[256];
    red[t] = s;
    __syncthreads();
    for (int off = 128; off > 0; off >>= 1) {
      if (t < off) red[t] += red[t + off];
      __syncthreads();
    }
    if (t == 0) ws[ASQ_OFF + k] = red[0];
  } else {
    const int c = (bid - K) * 256 + t;
    #pragma unroll
    for (int k = 0; k < K; k++)
      ws[WT_OFF + c * 12 + k] = 2.f * w_land[k * C + c];
    ws[WT_OFF + c * 12 + K] = 0.f;
  }
}

// ---------------------------------------------------------------- K1: maps + attn
// grid = B*13 blocks of 512 threads. Wave g handles channels c == g (mod 8);
// lane owns one hw position. logits = sum_c 2*w[k][c]*x[c] - a_sq[k]  (b_sq
// cancels in the K-softmax). Per-thread softmax over K=11 registers.
// (Round-2 note: 16x48-wide retile regressed — reverted to this known-good form.)
__global__ __launch_bounds__(512) void k1_maps(const float* __restrict__ x,
                                               const float* __restrict__ ws,
                                               float* __restrict__ maps_out,
                                               float* __restrict__ attn_out) {
  const int bid  = blockIdx.x;
  const int b    = bid / 13;
  const int tile = bid % 13;
  const int t    = threadIdx.x;
  const int g    = __builtin_amdgcn_readfirstlane(t >> 6);  // wave id, uniform
  const int hwl  = t & 63;
  const int hw   = tile * 64 + hwl;
  const int hwc  = hw < HW ? hw : HW - 1;  // clamp OOB loads, results discarded

  const float* xp  = x + (size_t)b * C * HW + hwc;
  const float* wT  = ws + WT_OFF;
  const float* asq = ws + ASQ_OFF;

  float acc[K];
  #pragma unroll
  for (int k = 0; k < K; k++) acc[k] = (g == 0) ? -asq[k] : 0.f;

  // 384 channels per thread, unroll 8 -> 8 coalesced loads in flight
  for (int i0 = 0; i0 < C / 8; i0 += 8) {
    float xv[8];
    #pragma unroll
    for (int u = 0; u < 8; u++)
      xv[u] = xp[(size_t)((i0 + u) * 8 + g) * HW];
    #pragma unroll
    for (int u = 0; u < 8; u++) {
      const float* wrow = wT + ((i0 + u) * 8 + g) * 12;  // uniform -> s_load
      #pragma unroll
      for (int k = 0; k < K; k++) acc[k] = fmaf(wrow[k], xv[u], acc[k]);
    }
  }

  __shared__ float abp[8][K][64];
  #pragma unroll
  for (int k = 0; k < K; k++) abp[g][k][hwl] = acc[k];
  __syncthreads();

  if (g == 0) {
    float l[K];
    #pragma unroll
    for (int k = 0; k < K; k++) {
      float s = 0.f;
      #pragma unroll
      for (int gg = 0; gg < 8; gg++) s += abp[gg][k][hwl];
      l[k] = s;
    }
    float m = l[0];
    #pragma unroll
    for (int k = 1; k < K; k++) m = fmaxf(m, l[k]);
    float z = 0.f;
    #pragma unroll
    for (int k = 0; k < K; k++) { l[k] = __expf(l[k] - m); z += l[k]; }
    const float inv = 1.f / z;
    const bool valid = hw < HW;
    #pragma unroll
    for (int k = 0; k < K; k++) {
      float r = l[k] * inv;
      if (valid) maps_out[((size_t)b * K + k) * HW + hw] = r;
      float v = valid ? r : 0.f;
      #pragma unroll
      for (int sh = 32; sh > 0; sh >>= 1) v += __shfl_xor(v, sh);
      if (hwl == 0) atomicAdd(&attn_out[b * K + k], v);
    }
  }
}

// ---------------------------------------------------------------- K2: all_features (+ fused fsum)
// grid = B*24, 256 threads. Block owns (b, 128-channel tile), streams hw in
// 64-chunks through an LDS transpose (row stride 68 floats = odd multiple of
// 16B -> conflict-free b128 reads). maps[b] lives in LDS, zero-padded past
// hw=784. Thread (p,q) owns channels {p, p+64} over hw-quarter q.
// Blocks walk b in reverse so the x re-read hits what K1 left in L3.
// Epilogue also emits fsum[b,c] = sum_k afm_modulated (replaces old k3).
// (Round-2 note: float4 register-prefetch staging regressed — reverted.)
constexpr int CT   = 128;
constexpr int XROW = 68;
constexpr int MROW = 832;  // 13*64

__global__ __launch_bounds__(256) void k2_feat(const float* __restrict__ x,
                                               const float* __restrict__ maps_g,
                                               const float* __restrict__ modulation,
                                               float* __restrict__ afm_out,
                                               float* __restrict__ fsum_out) {
  __shared__ __align__(16) float maps_s[K * MROW];   // 36.6 KB
  __shared__ __align__(16) float lds_x[CT * XROW];   // 34.8 KB

  const int bid = blockIdx.x;
  const int b   = (B - 1) - (bid / (C / CT));
  const int c0  = (bid % (C / CT)) * CT;
  const int t   = threadIdx.x;

  for (int k = 0; k < K; k++)
    for (int i = t; i < MROW; i += 256)
      maps_s[k * MROW + i] = (i < HW) ? maps_g[((size_t)b * K + k) * HW + i] : 0.f;

  const int hwl = t & 63;
  const int rr  = t >> 6;
  const int p   = t & 63;
  const int q   = t >> 6;

  float f0[K], f1[K];
  #pragma unroll
  for (int k = 0; k < K; k++) { f0[k] = 0.f; f1[k] = 0.f; }

  const float* xb = x + (size_t)b * C * HW;

  for (int ch = 0; ch < 13; ch++) {
    const int hbase = ch * 64;
    __syncthreads();  // covers maps_s on ch=0, lds_x reuse afterwards
    #pragma unroll
    for (int i = 0; i < CT / 4; i++) {
      const int r = rr + i * 4;
      int hwp = hbase + hwl;
      if (hwp >= HW) hwp = HW - 1;  // clamped garbage * maps_pad(0) = 0
      lds_x[r * XROW + hwl] = xb[(size_t)(c0 + r) * HW + hwp];
    }
    __syncthreads();
    #pragma unroll
    for (int hg = 0; hg < 4; hg++) {
      const int hoff = (q * 4 + hg) * 4;
      const float4 xa = *(const float4*)&lds_x[p * XROW + hoff];
      const float4 xc = *(const float4*)&lds_x[(p + 64) * XROW + hoff];
      #pragma unroll
      for (int k = 0; k < K; k++) {
        const float4 m4 = *(const float4*)&maps_s[k * MROW + hbase + hoff];
        f0[k] += xa.x * m4.x + xa.y * m4.y + xa.z * m4.z + xa.w * m4.w;
        f1[k] += xc.x * m4.x + xc.y * m4.y + xc.z * m4.z + xc.w * m4.w;
      }
    }
  }

  // reduce the 4 hw-quarters via LDS, then modulate + /HW and store
  __syncthreads();
  float* fbuf = lds_x;  // 4*128*11 = 5632 floats <= 8704 available
  #pragma unroll
  for (int k = 0; k < K; k++) {
    fbuf[(q * CT + p) * K + k]      = f0[k];
    fbuf[(q * CT + p + 64) * K + k] = f1[k];
  }
  __syncthreads();

  const float inv_hw = 1.f / (float)HW;
  for (int o = t; o < CT * K; o += 256) {
    float s = fbuf[o] + fbuf[CT * K + o] + fbuf[2 * CT * K + o] + fbuf[3 * CT * K + o];
    afm_out[(size_t)b * C * K + c0 * K + o] = s * inv_hw * modulation[c0 * K + o];
  }
  // fused k3: fsum[b,c] = sum_k afm_modulated[b,c,k]
  for (int cl = t; cl < CT; cl += 256) {
    float s = 0.f;
    #pragma unroll
    for (int k = 0; k < K; k++) {
      const int o = cl * K + k;
      float v = fbuf[o] + fbuf[CT * K + o] + fbuf[2 * CT * K + o] + fbuf[3 * CT * K + o];
      s += v * modulation[c0 * K + o];
    }
    fsum_out[(size_t)b * C + c0 + cl] = s * inv_hw;
  }
}

// ---------------------------------------------------------------- K4: scores
// grid = B*25 blocks; 256 threads = 8 class-rows x 32 lanes. fsum[b] staged in
// LDS (broadcast), w_cls rows read as float4 (coalesced 16B/lane), 32-lane
// shuffle reduction.
__global__ __launch_bounds__(256) void k4_scores(const float* __restrict__ fsum,
                                                 const float* __restrict__ w_cls,
                                                 float* __restrict__ scores) {
  __shared__ __align__(16) float fs[C];  // 12 KB
  const int bid = blockIdx.x;
  const int b   = bid / (NC / 8);
  const int nt  = bid % (NC / 8);
  const int t   = threadIdx.x;

  for (int i = t; i < C; i += 256) fs[i] = fsum[b * C + i];
  __syncthreads();

  const int nl = t >> 5, lane = t & 31;
  const int n = nt * 8 + nl;
  const float4* wr4 = (const float4*)(w_cls + (size_t)n * C);
  const float4* fs4 = (const float4*)fs;
  float acc = 0.f;
  for (int c4 = lane; c4 < C / 4; c4 += 32) {
    const float4 w4 = wr4[c4];
    const float4 f4 = fs4[c4];
    acc += w4.x * f4.x + w4.y * f4.y + w4.z * f4.z + w4.w * f4.w;
  }
  #pragma unroll
  for (int sh = 16; sh > 0; sh >>= 1) acc += __shfl_xor(acc, sh);
  if (lane == 0) scores[b * NC + n] = acc;
}

// ----------------------------------------------------------------
extern "C" void kernel_launch(void* const* d_in, const int* in_sizes, int n_in,
                              void* d_out, int out_size, void* d_ws, size_t ws_size,
                              hipStream_t stream) {
  const float* x          = (const float*)d_in[0];
  const float* w_land     = (const float*)d_in[1];
  const float* modulation = (const float*)d_in[2];
  const float* w_cls      = (const float*)d_in[3];

  float* out    = (float*)d_out;
  float* afm    = out + AFM_OFF;
  float* scores = out + SCORES_OFF;
  float* maps   = out + MAPS_OFF;
  float* attn   = out + ATTN_OFF;
  float* ws     = (float*)d_ws;

  hipMemsetAsync(attn, 0, B * K * sizeof(float), stream);            // attn via atomics
  k0_prep  <<<K + C / 256,     256, 0, stream>>>(w_land, ws);
  k1_maps  <<<B * 13,          512, 0, stream>>>(x, ws, maps, attn);
  k2_feat  <<<B * (C / CT),    256, 0, stream>>>(x, maps, modulation, afm, ws + FSUM_OFF);
  k4_scores<<<B * (NC / 8),    256, 0, stream>>>(ws + FSUM_OFF, w_cls, scores);
}

// Round 4
// 517.745 us; speedup vs baseline: 1.2080x; 1.0344x over previous
//
#include <hip/hip_runtime.h>

constexpr int B  = 32;
constexpr int C  = 3072;
constexpr int HW = 784;
constexpr int K  = 11;
constexpr int NC = 200;

// d_out layout (floats), concatenated in reference return order
constexpr int AFM_OFF    = 0;         // B*C*K  = 1081344
constexpr int SCORES_OFF = 1081344;   // B*NC   = 6400
constexpr int MAPS_OFF   = 1087744;   // B*K*HW = 275968
constexpr int ATTN_OFF   = 1363712;   // B*K    = 352

// ws layout (floats)
constexpr int WT_OFF   = 0;       // C*12 : w_land transposed, scaled by 2, padded to 12/row
constexpr int ASQ_OFF  = 36864;   // 16   : a_sq[k]
constexpr int FSUM_OFF = 36880;   // B*C  : sum over k of afm (modulated, /HW)

// ---------------------------------------------------------------- K0: prep
// blocks 0..10: a_sq[k] = sum_c w[k][c]^2 ; blocks 11..22: wT[c][k] = 2*w[k][c];
// block 23: zero attn (replaces the separate hipMemsetAsync dispatch).
__global__ __launch_bounds__(256) void k0_prep(const float* __restrict__ w_land,
                                               float* __restrict__ ws,
                                               float* __restrict__ attn_out) {
  const int bid = blockIdx.x;
  const int t = threadIdx.x;
  if (bid < K) {
    const int k = bid;
    float s = 0.f;
    for (int c = t; c < C; c += 256) {
      float v = w_land[k * C + c];
      s = fmaf(v, v, s);
    }
    __shared__ float red[256];
    red[t] = s;
    __syncthreads();
    for (int off = 128; off > 0; off >>= 1) {
      if (t < off) red[t] += red[t + off];
      __syncthreads();
    }
    if (t == 0) ws[ASQ_OFF + k] = red[0];
  } else if (bid < K + C / 256) {
    const int c = (bid - K) * 256 + t;
    #pragma unroll
    for (int k = 0; k < K; k++)
      ws[WT_OFF + c * 12 + k] = 2.f * w_land[k * C + c];
    ws[WT_OFF + c * 12 + K] = 0.f;
  } else {
    if (t < B * K + 96) {  // 352 + pad; attn region is B*K floats
      if (t < B * K) attn_out[t] = 0.f;
    }
  }
}

// ---------------------------------------------------------------- K1: maps + attn
// grid = B*13 blocks of 512 threads. Wave g handles channels c == g (mod 8);
// lane owns one hw position. logits = sum_c 2*w[k][c]*x[c] - a_sq[k]  (b_sq
// cancels in the K-softmax). Per-thread softmax over K=11 registers.
// (Round-2 note: 16x48 retile + contiguous wave slabs regressed — keep this form.)
__global__ __launch_bounds__(512) void k1_maps(const float* __restrict__ x,
                                               const float* __restrict__ ws,
                                               float* __restrict__ maps_out,
                                               float* __restrict__ attn_out) {
  const int bid  = blockIdx.x;
  const int b    = bid / 13;
  const int tile = bid % 13;
  const int t    = threadIdx.x;
  const int g    = __builtin_amdgcn_readfirstlane(t >> 6);  // wave id, uniform
  const int hwl  = t & 63;
  const int hw   = tile * 64 + hwl;
  const int hwc  = hw < HW ? hw : HW - 1;  // clamp OOB loads, results discarded

  const float* xp  = x + (size_t)b * C * HW + hwc;
  const float* wT  = ws + WT_OFF;
  const float* asq = ws + ASQ_OFF;

  float acc[K];
  #pragma unroll
  for (int k = 0; k < K; k++) acc[k] = (g == 0) ? -asq[k] : 0.f;

  // 384 channels per thread, unroll 8 -> 8 coalesced loads in flight
  for (int i0 = 0; i0 < C / 8; i0 += 8) {
    float xv[8];
    #pragma unroll
    for (int u = 0; u < 8; u++)
      xv[u] = xp[(size_t)((i0 + u) * 8 + g) * HW];
    #pragma unroll
    for (int u = 0; u < 8; u++) {
      const float* wrow = wT + ((i0 + u) * 8 + g) * 12;  // uniform -> s_load
      #pragma unroll
      for (int k = 0; k < K; k++) acc[k] = fmaf(wrow[k], xv[u], acc[k]);
    }
  }

  __shared__ float abp[8][K][64];
  #pragma unroll
  for (int k = 0; k < K; k++) abp[g][k][hwl] = acc[k];
  __syncthreads();

  if (g == 0) {
    float l[K];
    #pragma unroll
    for (int k = 0; k < K; k++) {
      float s = 0.f;
      #pragma unroll
      for (int gg = 0; gg < 8; gg++) s += abp[gg][k][hwl];
      l[k] = s;
    }
    float m = l[0];
    #pragma unroll
    for (int k = 1; k < K; k++) m = fmaxf(m, l[k]);
    float z = 0.f;
    #pragma unroll
    for (int k = 0; k < K; k++) { l[k] = __expf(l[k] - m); z += l[k]; }
    const float inv = 1.f / z;
    const bool valid = hw < HW;
    #pragma unroll
    for (int k = 0; k < K; k++) {
      float r = l[k] * inv;
      if (valid) maps_out[((size_t)b * K + k) * HW + hw] = r;
      float v = valid ? r : 0.f;
      #pragma unroll
      for (int sh = 32; sh > 0; sh >>= 1) v += __shfl_xor(v, sh);
      if (hwl == 0) atomicAdd(&attn_out[b * K + k], v);
    }
  }
}

// ---------------------------------------------------------------- K2: all_features (+ fused fsum)
// grid = B*24, 256 threads. Block owns (b, 128-channel tile), streams hw in
// 64-chunks through an LDS transpose (row stride 68 floats = odd multiple of
// 16B -> conflict-free b128 reads). maps[b] lives in LDS, zero-padded past
// hw=784. Staging is float4 (8 dwordx4/thread instead of 32 dword), same
// barrier structure as the known-good scalar version (no register prefetch —
// that regressed in round 2). Thread (p,q) owns channels {p, p+64} over
// hw-quarter q. Blocks walk b in reverse so the x re-read hits what K1 left
// in L3. Epilogue also emits fsum[b,c] = sum_k afm_modulated (old k3).
constexpr int CT   = 128;
constexpr int XROW = 68;
constexpr int MROW = 832;  // 13*64

__global__ __launch_bounds__(256) void k2_feat(const float* __restrict__ x,
                                               const float* __restrict__ maps_g,
                                               const float* __restrict__ modulation,
                                               float* __restrict__ afm_out,
                                               float* __restrict__ fsum_out) {
  __shared__ __align__(16) float maps_s[K * MROW];   // 36.6 KB
  __shared__ __align__(16) float lds_x[CT * XROW];   // 34.8 KB

  const int bid = blockIdx.x;
  const int b   = (B - 1) - (bid / (C / CT));
  const int c0  = (bid % (C / CT)) * CT;
  const int t   = threadIdx.x;

  // ---- stage maps as float4, zero-padded to MROW (verified in round 2)
  if (t < MROW / 4) {
    #pragma unroll
    for (int k = 0; k < K; k++) {
      float4 v;
      if (t < HW / 4)
        v = ((const float4*)(maps_g + ((size_t)b * K + k) * HW))[t];
      else
        v = make_float4(0.f, 0.f, 0.f, 0.f);
      ((float4*)(maps_s + k * MROW))[t] = v;
    }
  }

  const int f4l  = t & 15;   // float4 column within 64-hw chunk
  const int rgrp = t >> 4;   // rows rgrp + j*16
  const int p    = t & 63;
  const int q    = t >> 6;

  const float4* xb4 = (const float4*)(x + (size_t)b * C * HW);  // rows of HW/4=196 f4

  float f0[K], f1[K];
  #pragma unroll
  for (int k = 0; k < K; k++) { f0[k] = 0.f; f1[k] = 0.f; }

  for (int ch = 0; ch < 13; ch++) {
    const int hbase = ch * 64;
    __syncthreads();  // covers maps_s on ch=0, lds_x reuse afterwards
    {
      int c4 = ch * 16 + f4l;
      if (c4 >= HW / 4) c4 = HW / 4 - 1;  // clamped garbage * maps_pad(0) = 0
      #pragma unroll
      for (int j = 0; j < 8; j++) {
        const float4 v = xb4[(size_t)(c0 + rgrp + j * 16) * (HW / 4) + c4];
        *(float4*)&lds_x[(rgrp + j * 16) * XROW + f4l * 4] = v;
      }
    }
    __syncthreads();
    #pragma unroll
    for (int hg = 0; hg < 4; hg++) {
      const int hoff = (q * 4 + hg) * 4;
      const float4 xa = *(const float4*)&lds_x[p * XROW + hoff];
      const float4 xc = *(const float4*)&lds_x[(p + 64) * XROW + hoff];
      #pragma unroll
      for (int k = 0; k < K; k++) {
        const float4 m4 = *(const float4*)&maps_s[k * MROW + hbase + hoff];
        f0[k] += xa.x * m4.x + xa.y * m4.y + xa.z * m4.z + xa.w * m4.w;
        f1[k] += xc.x * m4.x + xc.y * m4.y + xc.z * m4.z + xc.w * m4.w;
      }
    }
  }

  // reduce the 4 hw-quarters via LDS, then modulate + /HW and store
  __syncthreads();
  float* fbuf = lds_x;  // 4*128*11 = 5632 floats <= 8704 available
  #pragma unroll
  for (int k = 0; k < K; k++) {
    fbuf[(q * CT + p) * K + k]      = f0[k];
    fbuf[(q * CT + p + 64) * K + k] = f1[k];
  }
  __syncthreads();

  const float inv_hw = 1.f / (float)HW;
  for (int o = t; o < CT * K; o += 256) {
    float s = fbuf[o] + fbuf[CT * K + o] + fbuf[2 * CT * K + o] + fbuf[3 * CT * K + o];
    afm_out[(size_t)b * C * K + c0 * K + o] = s * inv_hw * modulation[c0 * K + o];
  }
  // fused k3: fsum[b,c] = sum_k afm_modulated[b,c,k]
  for (int cl = t; cl < CT; cl += 256) {
    float s = 0.f;
    #pragma unroll
    for (int k = 0; k < K; k++) {
      const int o = cl * K + k;
      float v = fbuf[o] + fbuf[CT * K + o] + fbuf[2 * CT * K + o] + fbuf[3 * CT * K + o];
      s += v * modulation[c0 * K + o];
    }
    fsum_out[(size_t)b * C + c0 + cl] = s * inv_hw;
  }
}

// ---------------------------------------------------------------- K4: scores
// grid = B*25 blocks; 256 threads = 8 class-rows x 32 lanes. fsum[b] staged in
// LDS (broadcast), w_cls rows read as float4 (coalesced 16B/lane), 32-lane
// shuffle reduction.
__global__ __launch_bounds__(256) void k4_scores(const float* __restrict__ fsum,
                                                 const float* __restrict__ w_cls,
                                                 float* __restrict__ scores) {
  __shared__ __align__(16) float fs[C];  // 12 KB
  const int bid = blockIdx.x;
  const int b   = bid / (NC / 8);
  const int nt  = bid % (NC / 8);
  const int t   = threadIdx.x;

  for (int i = t; i < C; i += 256) fs[i] = fsum[b * C + i];
  __syncthreads();

  const int nl = t >> 5, lane = t & 31;
  const int n = nt * 8 + nl;
  const float4* wr4 = (const float4*)(w_cls + (size_t)n * C);
  const float4* fs4 = (const float4*)fs;
  float acc = 0.f;
  for (int c4 = lane; c4 < C / 4; c4 += 32) {
    const float4 w4 = wr4[c4];
    const float4 f4 = fs4[c4];
    acc += w4.x * f4.x + w4.y * f4.y + w4.z * f4.z + w4.w * f4.w;
  }
  #pragma unroll
  for (int sh = 16; sh > 0; sh >>= 1) acc += __shfl_xor(acc, sh);
  if (lane == 0) scores[b * NC + n] = acc;
}

// ----------------------------------------------------------------
extern "C" void kernel_launch(void* const* d_in, const int* in_sizes, int n_in,
                              void* d_out, int out_size, void* d_ws, size_t ws_size,
                              hipStream_t stream) {
  const float* x          = (const float*)d_in[0];
  const float* w_land     = (const float*)d_in[1];
  const float* modulation = (const float*)d_in[2];
  const float* w_cls      = (const float*)d_in[3];

  float* out    = (float*)d_out;
  float* afm    = out + AFM_OFF;
  float* scores = out + SCORES_OFF;
  float* maps   = out + MAPS_OFF;
  float* attn   = out + ATTN_OFF;
  float* ws     = (float*)d_ws;

  k0_prep  <<<K + C / 256 + 1, 256, 0, stream>>>(w_land, ws, attn);  // +attn zero
  k1_maps  <<<B * 13,          512, 0, stream>>>(x, ws, maps, attn);
  k2_feat  <<<B * (C / CT),    256, 0, stream>>>(x, maps, modulation, afm, ws + FSUM_OFF);
  k4_scores<<<B * (NC / 8),    256, 0, stream>>>(ws + FSUM_OFF, w_cls, scores);
}